// Round 17
// baseline (1587.719 us; speedup 1.0000x reference)
//
#include <hip/hip_runtime.h>
#include <hip/hip_bf16.h>
#include <stdint.h>

typedef float f32x4 __attribute__((ext_vector_type(4)));
typedef short s16x8 __attribute__((ext_vector_type(8)));
typedef int i32x8 __attribute__((ext_vector_type(8)));
typedef unsigned long long u64;

#define INV_SCALE (1.0f / 1024.0f)  // W pre-scaled x64, h x16
#define SCALE_ONE 0x7F7F7F7F        // E8M0 1.0 in every byte
#define LOG2E 1.4426950408889634f

__device__ __forceinline__ float sigm(float x) {
  return __builtin_amdgcn_rcpf(1.f + __builtin_amdgcn_exp2f(-LOG2E * x));
}
__device__ __forceinline__ ushort f2bf(float f) {
  union { float f; uint32_t u; } v; v.f = f;
  return (ushort)((v.u + 0x7FFFu + ((v.u >> 16) & 1)) >> 16);
}
__device__ __forceinline__ float bf2f(ushort b) {
  union { uint32_t u; float f; } v; v.u = ((uint32_t)b) << 16; return v.f;
}

// ---------------- prep: bias sums + flag reset ----------------
__global__ __launch_bounds__(256) void prep_kernel(
    const float* __restrict__ bih0, const float* __restrict__ bhh0,
    const float* __restrict__ bih1, const float* __restrict__ bhh1,
    float* __restrict__ b0p, float* __restrict__ b1p,
    unsigned int* __restrict__ done0)
{
  const int stride = gridDim.x * blockDim.x;
  const int gid = blockIdx.x * blockDim.x + threadIdx.x;
  for (int i = gid; i < 1024; i += stride) {
    int p = ((i & 3) << 8) | (i >> 2);
    b0p[i] = bih0[p] + bhh0[p];   // gate-interleaved (producer xp0 epilogue)
    b1p[i] = bih1[p] + bhh1[p];   // gate-interleaved (consumer epilogue)
  }
  for (int i = gid; i < 128; i += stride) done0[i] = 0;  // reset chunk flags each launch
}

// ---------------- mega: layer-0 producer (WG 0-127) || layer-1 consumer (WG 128-255) ----------------
// R16 structure with CHUNK=32 (NC=16): halves the count of per-chunk pipeline overheads
// (publish drain, flag visibility, poll, stage latency, extra barriers).
__global__ __launch_bounds__(1024) void mega_scan(
    const int* __restrict__ x, const float* __restrict__ emb,
    const float* __restrict__ Wih0, const float* __restrict__ Wih1,
    const float* __restrict__ b0p,
    const float* __restrict__ Whh0, const float* __restrict__ Whh1,
    const float* __restrict__ b1p,
    u64* __restrict__ hs64, unsigned int* __restrict__ done0,
    const float* __restrict__ fcw, const float* __restrict__ fcb,
    float* __restrict__ out)
{
  __shared__ __align__(16) unsigned char smem[84112];
  ushort* xpcu = (ushort*)smem;                 // [32][1024] bf16 xp chunk          (64 KB)
  unsigned char* h0l = smem + 65536;            // [32][272] emb-bf16 / fp8 h0 rows  (8.5 KB)
  unsigned char* h0pub = smem + 74240;          // [32][256] fp8 h0 publish buffer   (8 KB)
  unsigned char* hbb = smem + 82432;            // [2][320]  h ping-pong fp8
  float* hf = (float*)(smem + 83072);           // [260]     final h f32

  const int tid = threadIdx.x;
  const int l = tid & 63, w = tid >> 6;
  const int lr = l & 15, lg = l >> 4;
  const bool is0 = blockIdx.x < 128;
  const int b = is0 ? blockIdx.x : (blockIdx.x - 128);
  const float* Whh = is0 ? Whh0 : Whh1;
  const int hcol = 16 * w + lr;

  // W_hh fragments (fp8 x64): gate s, k-chunk kc; B col = 256*s + hcol, k = kc*128 + lg*32 + j
  i32x8 wf[4][2];
#pragma unroll
  for (int s = 0; s < 4; ++s) {
    const int n = 256 * s + hcol;
#pragma unroll
    for (int kc = 0; kc < 2; ++kc) {
      i32x8 r;
#pragma unroll
      for (int d = 0; d < 8; ++d) {
        const f32x4 v = *(const f32x4*)(Whh + (size_t)n * 256 + kc * 128 + lg * 32 + d * 4);
        int q = __builtin_amdgcn_cvt_pk_fp8_f32(v[0] * 64.f, v[1] * 64.f, 0, false);
        q = __builtin_amdgcn_cvt_pk_fp8_f32(v[2] * 64.f, v[3] * 64.f, q, true);
        r[d] = q;
      }
      wf[s][kc] = r;
    }
  }

  if (tid < 320) hbb[tid] = 0;  // h(-1) = 0 (buffer 0)
  float cc = 0.f;

  if (is0) {
    // ================= layer 0 producer =================
    float bias0n[4];
#pragma unroll
    for (int nt = 0; nt < 4; ++nt) bias0n[nt] = b0p[64 * w + nt * 16 + lr];
    // W_ih0 fragments (bf16): B row j = 64w + nt*16 + lr -> raw row p = ((j&3)<<8)|(j>>2)
    s16x8 w0f[4][4];
#pragma unroll
    for (int nt = 0; nt < 4; ++nt) {
      const int j = 64 * w + nt * 16 + lr;
      const int p = ((j & 3) << 8) | (j >> 2);
#pragma unroll
      for (int ks = 0; ks < 4; ++ks) {
        const float* src = Wih0 + (size_t)p * 128 + ks * 32 + lg * 8;
        const f32x4 v0 = *(const f32x4*)src;
        const f32x4 v1 = *(const f32x4*)(src + 4);
        s16x8 r;
        r[0] = (short)f2bf(v0[0]); r[1] = (short)f2bf(v0[1]);
        r[2] = (short)f2bf(v0[2]); r[3] = (short)f2bf(v0[3]);
        r[4] = (short)f2bf(v1[0]); r[5] = (short)f2bf(v1[1]);
        r[6] = (short)f2bf(v1[2]); r[7] = (short)f2bf(v1[3]);
        w0f[nt][ks] = r;
      }
    }
    int rowidx0 = x[b * 512 + w];       // chunk 0 rows w and 16+w, prefetched
    int rowidx1 = x[b * 512 + 16 + w];
    __syncthreads();
    for (int c = 0; c < 16; ++c) {
      // --- emb gather: wave w stages timesteps w and 16+w as bf16 into h0l (NT loads) ---
      {
        const u64 e0 = __builtin_nontemporal_load(
            (const u64*)(emb + (size_t)rowidx0 * 128 + l * 2));
        const u64 e1 = __builtin_nontemporal_load(
            (const u64*)(emb + (size_t)rowidx1 * 128 + l * 2));
        union { u64 q; float f[2]; } ev0, ev1; ev0.q = e0; ev1.q = e1;
        *(uint*)(h0l + w * 272 + l * 4) =
            (uint)f2bf(ev0.f[0]) | ((uint)f2bf(ev0.f[1]) << 16);
        *(uint*)(h0l + (16 + w) * 272 + l * 4) =
            (uint)f2bf(ev1.f[0]) | ((uint)f2bf(ev1.f[1]) << 16);
        if (c < 15) {
          rowidx0 = x[b * 512 + (c + 1) * 32 + w];
          rowidx1 = x[b * 512 + (c + 1) * 32 + 16 + w];
        }
      }
      __syncthreads();
      // --- chunk xp0 GEMM: two sequential M=16 tiles (caps register pressure) ---
#pragma unroll
      for (int mt = 0; mt < 2; ++mt) {
        s16x8 av[4];
#pragma unroll
        for (int ks = 0; ks < 4; ++ks)
          av[ks] = *(const s16x8*)(h0l + (mt * 16 + lr) * 272 + ks * 64 + lg * 16);
        f32x4 ga0 = (f32x4)0.f, ga1 = (f32x4)0.f, ga2 = (f32x4)0.f, ga3 = (f32x4)0.f;
#pragma unroll
        for (int ks = 0; ks < 4; ++ks) {
          ga0 = __builtin_amdgcn_mfma_f32_16x16x32_bf16(av[ks], w0f[0][ks], ga0, 0, 0, 0);
          ga1 = __builtin_amdgcn_mfma_f32_16x16x32_bf16(av[ks], w0f[1][ks], ga1, 0, 0, 0);
          ga2 = __builtin_amdgcn_mfma_f32_16x16x32_bf16(av[ks], w0f[2][ks], ga2, 0, 0, 0);
          ga3 = __builtin_amdgcn_mfma_f32_16x16x32_bf16(av[ks], w0f[3][ks], ga3, 0, 0, 0);
        }
#pragma unroll
        for (int i = 0; i < 4; ++i) {
          const int row = mt * 16 + 4 * lg + i;
          xpcu[row * 1024 + 64 * w + lr]      = f2bf(ga0[i] + bias0n[0]);
          xpcu[row * 1024 + 64 * w + 16 + lr] = f2bf(ga1[i] + bias0n[1]);
          xpcu[row * 1024 + 64 * w + 32 + lr] = f2bf(ga2[i] + bias0n[2]);
          xpcu[row * 1024 + 64 * w + 48 + lr] = f2bf(ga3[i] + bias0n[3]);
        }
      }
      __syncthreads();
      // --- 32 recurrent steps (R7-verified structure; publish buffered to LDS) ---
      for (int ts = 0; ts < 32; ++ts) {
        const unsigned char* hr = hbb + ((ts & 1) * 320);
        unsigned char* hw = hbb + (((ts & 1) ^ 1) * 320);
        i32x8 af[2];
#pragma unroll
        for (int kc = 0; kc < 2; ++kc) {
          const uint4* p = (const uint4*)(hr + kc * 128 + lg * 32);
          uint4 lo = p[0], hi = p[1];
          i32x8 a;
          a[0] = lo.x; a[1] = lo.y; a[2] = lo.z; a[3] = lo.w;
          a[4] = hi.x; a[5] = hi.y; a[6] = hi.z; a[7] = hi.w;
          af[kc] = a;
        }
        f32x4 acc0 = (f32x4)0.f, acc1 = (f32x4)0.f, acc2 = (f32x4)0.f, acc3 = (f32x4)0.f;
#pragma unroll
        for (int kc = 0; kc < 2; ++kc) {
          acc0 = __builtin_amdgcn_mfma_scale_f32_16x16x128_f8f6f4(af[kc], wf[0][kc], acc0, 0, 0, 0, SCALE_ONE, 0, SCALE_ONE);
          acc1 = __builtin_amdgcn_mfma_scale_f32_16x16x128_f8f6f4(af[kc], wf[1][kc], acc1, 0, 0, 0, SCALE_ONE, 0, SCALE_ONE);
          acc2 = __builtin_amdgcn_mfma_scale_f32_16x16x128_f8f6f4(af[kc], wf[2][kc], acc2, 0, 0, 0, SCALE_ONE, 0, SCALE_ONE);
          acc3 = __builtin_amdgcn_mfma_scale_f32_16x16x128_f8f6f4(af[kc], wf[3][kc], acc3, 0, 0, 0, SCALE_ONE, 0, SCALE_ONE);
        }
        const uint2 xpv = *(const uint2*)(xpcu + ts * 1024 + (hcol << 2));
        const uint word = (lg & 2) ? xpv.y : xpv.x;
        const uint h16 = (lg & 1) ? (word >> 16) : (word & 0xFFFFu);
        union { uint32_t u; float f; } xf; xf.u = h16 << 16;
        const float accsel = (lg & 2) ? ((lg & 1) ? acc3[0] : acc2[0])
                                      : ((lg & 1) ? acc1[0] : acc0[0]);
        const float p = accsel * INV_SCALE + xf.f;
        const float kk2 = (lg == 2) ? (2.f * LOG2E) : LOG2E;
        const float mm = (lg == 2) ? 2.f : 1.f;
        const float ex = __builtin_amdgcn_exp2f(kk2 * p);
        const float v = 1.f - mm * __builtin_amdgcn_rcpf(ex + 1.f);
        const float sf = __shfl(v, lr + 16);
        const float tg = __shfl(v, lr + 32);
        const float so = __shfl(v, lr + 48);
        cc = sf * cc + v * tg;
        const float e2 = __builtin_amdgcn_exp2f(2.f * LOG2E * cc);
        const float th = 1.f - 2.f * __builtin_amdgcn_rcpf(e2 + 1.f);
        const float h = so * th;
        if (lg == 0) {
          int q = __builtin_amdgcn_cvt_pk_fp8_f32(h * 16.f, h * 16.f, 0, false);
          hw[hcol] = (unsigned char)(q & 0xFF);
          h0pub[ts * 256 + hcol] = (unsigned char)(q & 0xFF);
        }
        __syncthreads();
      }
      // --- burst publish: 1024 contiguous u64 agent-scope stores (one per thread) ---
      {
        const int r = tid >> 5, kq = tid & 31;
        const u64 v = *(const u64*)(h0pub + r * 256 + (kq << 3));
        __hip_atomic_store(hs64 + ((size_t)b * 16 + c) * 1024 + tid, v,
                           __ATOMIC_RELAXED, __HIP_MEMORY_SCOPE_AGENT);
      }
      __syncthreads();  // per-wave vmcnt drain: publish complete before flag
      if (tid == 0)
        __hip_atomic_store(done0 + b, (unsigned)(c + 1),
                           __ATOMIC_RELAXED, __HIP_MEMORY_SCOPE_AGENT);
    }
  } else {
    // ================= layer 1 consumer =================
    const f32x4 bias = *(const f32x4*)(b1p + (hcol << 2));
    // W_ih1 fragments (fp8 x64): exact wf loader applied to Wih1
    i32x8 w1f[4][2];
#pragma unroll
    for (int s = 0; s < 4; ++s) {
      const int n = 256 * s + hcol;
#pragma unroll
      for (int kc = 0; kc < 2; ++kc) {
        i32x8 r;
#pragma unroll
        for (int d = 0; d < 8; ++d) {
          const f32x4 v = *(const f32x4*)(Wih1 + (size_t)n * 256 + kc * 128 + lg * 32 + d * 4);
          int q = __builtin_amdgcn_cvt_pk_fp8_f32(v[0] * 64.f, v[1] * 64.f, 0, false);
          q = __builtin_amdgcn_cvt_pk_fp8_f32(v[2] * 64.f, v[3] * 64.f, q, true);
          r[d] = q;
        }
        w1f[s][kc] = r;
      }
    }
    __syncthreads();
    for (int c = 0; c < 16; ++c) {
      if (tid == 0) {
        while (__hip_atomic_load(done0 + b, __ATOMIC_RELAXED, __HIP_MEMORY_SCOPE_AGENT)
               < (unsigned)(c + 1))
          __builtin_amdgcn_s_sleep(8);
      }
      __syncthreads();
      // stage 32x256 fp8 h0 chunk -> LDS rows (pad 272), contiguous u64 atomic loads
      {
        const int r = tid >> 5, kq = tid & 31;
        const u64 v = __hip_atomic_load(
            hs64 + ((size_t)b * 16 + c) * 1024 + tid,
            __ATOMIC_RELAXED, __HIP_MEMORY_SCOPE_AGENT);
        *(u64*)(h0l + r * 272 + (kq << 3)) = v;
      }
      __syncthreads();
      // chunk GEMM: two sequential M=16 tiles, A from LDS, B = w1f registers
#pragma unroll
      for (int mt = 0; mt < 2; ++mt) {
        f32x4 ga0 = (f32x4)0.f, ga1 = (f32x4)0.f, ga2 = (f32x4)0.f, ga3 = (f32x4)0.f;
#pragma unroll
        for (int kc = 0; kc < 2; ++kc) {
          const uint4* ap = (const uint4*)(h0l + (mt * 16 + lr) * 272 + (kc << 7) + (lg << 5));
          uint4 alo = ap[0], ahi = ap[1];
          i32x8 a;
          a[0] = alo.x; a[1] = alo.y; a[2] = alo.z; a[3] = alo.w;
          a[4] = ahi.x; a[5] = ahi.y; a[6] = ahi.z; a[7] = ahi.w;
          ga0 = __builtin_amdgcn_mfma_scale_f32_16x16x128_f8f6f4(a, w1f[0][kc], ga0, 0, 0, 0, SCALE_ONE, 0, SCALE_ONE);
          ga1 = __builtin_amdgcn_mfma_scale_f32_16x16x128_f8f6f4(a, w1f[1][kc], ga1, 0, 0, 0, SCALE_ONE, 0, SCALE_ONE);
          ga2 = __builtin_amdgcn_mfma_scale_f32_16x16x128_f8f6f4(a, w1f[2][kc], ga2, 0, 0, 0, SCALE_ONE, 0, SCALE_ONE);
          ga3 = __builtin_amdgcn_mfma_scale_f32_16x16x128_f8f6f4(a, w1f[3][kc], ga3, 0, 0, 0, SCALE_ONE, 0, SCALE_ONE);
        }
#pragma unroll
        for (int i = 0; i < 4; ++i) {
          const int row = mt * 16 + (lg << 2) + i;
          union { uint2 u; ushort s[4]; } pk;
          pk.s[0] = f2bf(ga0[i] * INV_SCALE + bias[0]);
          pk.s[1] = f2bf(ga1[i] * INV_SCALE + bias[1]);
          pk.s[2] = f2bf(ga2[i] * INV_SCALE + bias[2]);
          pk.s[3] = f2bf(ga3[i] * INV_SCALE + bias[3]);
          *(uint2*)(xpcu + row * 1024 + (hcol << 2)) = pk.u;
        }
      }
      __syncthreads();
      // 32 recurrent steps (R7-verified structure, xp from LDS gate-interleaved)
      for (int ts = 0; ts < 32; ++ts) {
        const unsigned char* hr = hbb + ((ts & 1) * 320);
        unsigned char* hw = hbb + (((ts & 1) ^ 1) * 320);
        i32x8 af[2];
#pragma unroll
        for (int kc = 0; kc < 2; ++kc) {
          const uint4* p = (const uint4*)(hr + kc * 128 + lg * 32);
          uint4 lo = p[0], hi = p[1];
          i32x8 a;
          a[0] = lo.x; a[1] = lo.y; a[2] = lo.z; a[3] = lo.w;
          a[4] = hi.x; a[5] = hi.y; a[6] = hi.z; a[7] = hi.w;
          af[kc] = a;
        }
        f32x4 acc0 = (f32x4)0.f, acc1 = (f32x4)0.f, acc2 = (f32x4)0.f, acc3 = (f32x4)0.f;
#pragma unroll
        for (int kc = 0; kc < 2; ++kc) {
          acc0 = __builtin_amdgcn_mfma_scale_f32_16x16x128_f8f6f4(af[kc], wf[0][kc], acc0, 0, 0, 0, SCALE_ONE, 0, SCALE_ONE);
          acc1 = __builtin_amdgcn_mfma_scale_f32_16x16x128_f8f6f4(af[kc], wf[1][kc], acc1, 0, 0, 0, SCALE_ONE, 0, SCALE_ONE);
          acc2 = __builtin_amdgcn_mfma_scale_f32_16x16x128_f8f6f4(af[kc], wf[2][kc], acc2, 0, 0, 0, SCALE_ONE, 0, SCALE_ONE);
          acc3 = __builtin_amdgcn_mfma_scale_f32_16x16x128_f8f6f4(af[kc], wf[3][kc], acc3, 0, 0, 0, SCALE_ONE, 0, SCALE_ONE);
        }
        const float xv = bf2f(xpcu[ts * 1024 + (hcol << 2) + lg]);
        const float accsel = (lg & 2) ? ((lg & 1) ? acc3[0] : acc2[0])
                                      : ((lg & 1) ? acc1[0] : acc0[0]);
        const float p = accsel * INV_SCALE + xv;
        const float kk2 = (lg == 2) ? (2.f * LOG2E) : LOG2E;
        const float mm = (lg == 2) ? 2.f : 1.f;
        const float ex = __builtin_amdgcn_exp2f(kk2 * p);
        const float v = 1.f - mm * __builtin_amdgcn_rcpf(ex + 1.f);
        const float sf = __shfl(v, lr + 16);
        const float tg = __shfl(v, lr + 32);
        const float so = __shfl(v, lr + 48);
        cc = sf * cc + v * tg;
        const float e2 = __builtin_amdgcn_exp2f(2.f * LOG2E * cc);
        const float th = 1.f - 2.f * __builtin_amdgcn_rcpf(e2 + 1.f);
        const float h = so * th;
        if (lg == 0) {
          int q = __builtin_amdgcn_cvt_pk_fp8_f32(h * 16.f, h * 16.f, 0, false);
          hw[hcol] = (unsigned char)(q & 0xFF);
          if (c == 15 && ts == 31) hf[hcol] = h;
        }
        __syncthreads();
      }
    }
    // fc epilogue
    if (w == 0) {
      float s = 0.f;
#pragma unroll
      for (int j = 0; j < 4; ++j) {
        const int k = j * 64 + l;
        s += hf[k] * fcw[k];
      }
      s += __shfl_xor(s, 1);
      s += __shfl_xor(s, 2);
      s += __shfl_xor(s, 4);
      s += __shfl_xor(s, 8);
      s += __shfl_xor(s, 16);
      s += __shfl_xor(s, 32);
      if (l == 0) out[b] = sigm(s + fcb[0]);
    }
  }
}

// ---------------- launch ----------------
extern "C" void kernel_launch(void* const* d_in, const int* in_sizes, int n_in,
                              void* d_out, int out_size, void* d_ws, size_t ws_size,
                              hipStream_t stream)
{
  const int*   x    = (const int*)d_in[0];
  const float* emb  = (const float*)d_in[1];
  const float* fcw  = (const float*)d_in[2];
  const float* fcb  = (const float*)d_in[3];
  const float* Wih0 = (const float*)d_in[4];
  const float* Whh0 = (const float*)d_in[5];
  const float* bih0 = (const float*)d_in[6];
  const float* bhh0 = (const float*)d_in[7];
  const float* Wih1 = (const float*)d_in[8];
  const float* Whh1 = (const float*)d_in[9];
  const float* bih1 = (const float*)d_in[10];
  const float* bhh1 = (const float*)d_in[11];

  char* ws = (char*)d_ws;
  size_t off = 0;
  auto alloc = [&](size_t bytes) {
    void* p = ws + off;
    off = (off + bytes + 255) & ~(size_t)255;
    return p;
  };
  u64*          hs64  = (u64*)alloc(128ull * 16 * 1024 * 8);
  float*        b0p   = (float*)alloc(1024 * 4);
  float*        b1p   = (float*)alloc(1024 * 4);
  unsigned int* done0 = (unsigned int*)alloc(128 * 4);

  prep_kernel<<<8, 256, 0, stream>>>(bih0, bhh0, bih1, bhh1, b0p, b1p, done0);
  mega_scan<<<256, 1024, 0, stream>>>(x, emb, Wih0, Wih1, b0p, Whh0, Whh1, b1p,
                                      hs64, done0, fcw, fcb, (float*)d_out);
}

// Round 18
// 816.914 us; speedup vs baseline: 1.9436x; 1.9436x over previous
//
#include <hip/hip_runtime.h>
#include <hip/hip_bf16.h>
#include <stdint.h>

typedef float f32x4 __attribute__((ext_vector_type(4)));
typedef short s16x8 __attribute__((ext_vector_type(8)));
typedef int i32x8 __attribute__((ext_vector_type(8)));
typedef unsigned long long u64;

#define INV_SCALE (1.0f / 1024.0f)  // W pre-scaled x64, h x16
#define SCALE_ONE 0x7F7F7F7F        // E8M0 1.0 in every byte
#define LOG2E 1.4426950408889634f

__device__ __forceinline__ float sigm(float x) {
  return __builtin_amdgcn_rcpf(1.f + __builtin_amdgcn_exp2f(-LOG2E * x));
}
__device__ __forceinline__ ushort f2bf(float f) {
  union { float f; uint32_t u; } v; v.f = f;
  return (ushort)((v.u + 0x7FFFu + ((v.u >> 16) & 1)) >> 16);
}
__device__ __forceinline__ float bf2f(ushort b) {
  union { uint32_t u; float f; } v; v.u = ((uint32_t)b) << 16; return v.f;
}

// ---------------- prep: weight permutes/converts + flag reset ----------------
__global__ __launch_bounds__(256) void prep_kernel(
    const float* __restrict__ Wih0, const float* __restrict__ Wih1,
    const float* __restrict__ bih0, const float* __restrict__ bhh0,
    const float* __restrict__ bih1, const float* __restrict__ bhh1,
    ushort* __restrict__ W0p, unsigned char* __restrict__ W1p8,
    float* __restrict__ b0p, float* __restrict__ b1p,
    unsigned int* __restrict__ done0)
{
  const int stride = gridDim.x * blockDim.x;
  const int gid = blockIdx.x * blockDim.x + threadIdx.x;
  // W0p[j][k] = Wih0[(j&3)*256 + (j>>2)][k]   (j = hid*4 + gate) bf16
  for (int i = gid; i < 1024 * 128; i += stride) {
    int j = i >> 7, k = i & 127;
    int p = ((j & 3) << 8) | (j >> 2);
    W0p[i] = f2bf(Wih0[p * 128 + k]);
  }
  // W1p8: RAW layout (row = gate*256+hid), fp8 e4m3 x64 (consumer chunk GEMM, R8-proven)
  for (int i = gid; i < 131072; i += stride) {
    int q = __builtin_amdgcn_cvt_pk_fp8_f32(Wih1[2 * i] * 64.f, Wih1[2 * i + 1] * 64.f, 0, false);
    ((ushort*)W1p8)[i] = (ushort)(q & 0xFFFF);
  }
  for (int i = gid; i < 1024; i += stride) {
    int p = ((i & 3) << 8) | (i >> 2);
    b0p[i] = bih0[p] + bhh0[p];   // gate-interleaved (producer xp0 epilogue)
    b1p[i] = bih1[p] + bhh1[p];   // gate-interleaved (consumer epilogue)
  }
  for (int i = gid; i < 128; i += stride) done0[i] = 0;  // reset chunk flags each launch
}

// ---------------- mega: layer-0 producer (WG 0-127) || layer-1 consumer (WG 128-255) ----------------
// R14 (best, 820us) + xp-read hoisted ABOVE the MFMA cluster in both step loops so the
// LDS read latency hides under the 8-MFMA chain instead of the gate phase's critical path.
__global__ __launch_bounds__(1024) void mega_scan(
    const int* __restrict__ x, const float* __restrict__ emb,
    const ushort* __restrict__ W0p, const float* __restrict__ b0p,
    const float* __restrict__ Whh0, const float* __restrict__ Whh1,
    const unsigned char* __restrict__ W1p8, const float* __restrict__ b1p,
    u64* __restrict__ hs64, unsigned int* __restrict__ done0,
    const float* __restrict__ fcw, const float* __restrict__ fcb,
    float* __restrict__ out)
{
  __shared__ __align__(16) unsigned char smem[42896];
  ushort* xpcu = (ushort*)smem;                 // [16][1024] bf16 xp chunk (both roles)
  unsigned char* h0l = smem + 32768;            // [16][272] emb-bf16 rows (prod) / fp8 h0 rows (cons)
  unsigned char* h0pub = smem + 37120;          // [16][256] fp8 h0 publish buffer (producer)
  unsigned char* hbb = smem + 41216;            // [2][320]  h ping-pong fp8
  float* hf = (float*)(smem + 41856);           // [260]     final h f32

  const int tid = threadIdx.x;
  const int l = tid & 63, w = tid >> 6;
  const int lr = l & 15, lg = l >> 4;
  const bool is0 = blockIdx.x < 128;
  const int b = is0 ? blockIdx.x : (blockIdx.x - 128);
  const float* Whh = is0 ? Whh0 : Whh1;
  const int hcol = 16 * w + lr;

  // W_hh fragments (fp8 x64): gate s, k-chunk kc; B col = 256*s + hcol, k = kc*128 + lg*32 + j
  i32x8 wf[4][2];
#pragma unroll
  for (int s = 0; s < 4; ++s) {
    const int n = 256 * s + hcol;
#pragma unroll
    for (int kc = 0; kc < 2; ++kc) {
      i32x8 r;
#pragma unroll
      for (int d = 0; d < 8; ++d) {
        const f32x4 v = *(const f32x4*)(Whh + (size_t)n * 256 + kc * 128 + lg * 32 + d * 4);
        int q = __builtin_amdgcn_cvt_pk_fp8_f32(v[0] * 64.f, v[1] * 64.f, 0, false);
        q = __builtin_amdgcn_cvt_pk_fp8_f32(v[2] * 64.f, v[3] * 64.f, q, true);
        r[d] = q;
      }
      wf[s][kc] = r;
    }
  }

  if (tid < 320) hbb[tid] = 0;  // h(-1) = 0 (buffer 0)
  float cc = 0.f;

  if (is0) {
    // ================= layer 0 producer =================
    float bias0n[4];
#pragma unroll
    for (int nt = 0; nt < 4; ++nt) bias0n[nt] = b0p[64 * w + nt * 16 + lr];
    __syncthreads();
    for (int c = 0; c < 32; ++c) {
      // --- emb gather: wave w stages timestep w's emb row as bf16 into h0l ---
      {
        const int rowidx = x[b * 512 + c * 16 + w];
        const float2 ev = *(const float2*)(emb + (size_t)rowidx * 128 + l * 2);
        const uint pk = (uint)f2bf(ev.x) | ((uint)f2bf(ev.y) << 16);
        *(uint*)(h0l + w * 272 + l * 4) = pk;
      }
      __syncthreads();
      // --- chunk xp0 GEMM: M=16 ts, N=64 cols/wave, K=128 bf16 ---
      {
        s16x8 av[4];
#pragma unroll
        for (int ks = 0; ks < 4; ++ks)
          av[ks] = *(const s16x8*)(h0l + lr * 272 + ks * 64 + lg * 16);
        f32x4 ga0 = (f32x4)0.f, ga1 = (f32x4)0.f, ga2 = (f32x4)0.f, ga3 = (f32x4)0.f;
#pragma unroll
        for (int ks = 0; ks < 4; ++ks) {
          const s16x8 bv0 = *(const s16x8*)(W0p + (size_t)(64 * w + lr) * 128 + ks * 32 + lg * 8);
          const s16x8 bv1 = *(const s16x8*)(W0p + (size_t)(64 * w + 16 + lr) * 128 + ks * 32 + lg * 8);
          const s16x8 bv2 = *(const s16x8*)(W0p + (size_t)(64 * w + 32 + lr) * 128 + ks * 32 + lg * 8);
          const s16x8 bv3 = *(const s16x8*)(W0p + (size_t)(64 * w + 48 + lr) * 128 + ks * 32 + lg * 8);
          ga0 = __builtin_amdgcn_mfma_f32_16x16x32_bf16(av[ks], bv0, ga0, 0, 0, 0);
          ga1 = __builtin_amdgcn_mfma_f32_16x16x32_bf16(av[ks], bv1, ga1, 0, 0, 0);
          ga2 = __builtin_amdgcn_mfma_f32_16x16x32_bf16(av[ks], bv2, ga2, 0, 0, 0);
          ga3 = __builtin_amdgcn_mfma_f32_16x16x32_bf16(av[ks], bv3, ga3, 0, 0, 0);
        }
#pragma unroll
        for (int i = 0; i < 4; ++i) {
          const int row = 4 * lg + i;
          xpcu[row * 1024 + 64 * w + lr]      = f2bf(ga0[i] + bias0n[0]);
          xpcu[row * 1024 + 64 * w + 16 + lr] = f2bf(ga1[i] + bias0n[1]);
          xpcu[row * 1024 + 64 * w + 32 + lr] = f2bf(ga2[i] + bias0n[2]);
          xpcu[row * 1024 + 64 * w + 48 + lr] = f2bf(ga3[i] + bias0n[3]);
        }
      }
      __syncthreads();
      // --- 16 recurrent steps (R7-verified structure; publish buffered to LDS) ---
      for (int ts = 0; ts < 16; ++ts) {
        const unsigned char* hr = hbb + ((ts & 1) * 320);
        unsigned char* hw = hbb + (((ts & 1) ^ 1) * 320);
        // xp read issued FIRST: its LDS latency hides under the MFMA chain
        const uint2 xpv = *(const uint2*)(xpcu + ts * 1024 + (hcol << 2));
        i32x8 af[2];
#pragma unroll
        for (int kc = 0; kc < 2; ++kc) {
          const uint4* p = (const uint4*)(hr + kc * 128 + lg * 32);
          uint4 lo = p[0], hi = p[1];
          i32x8 a;
          a[0] = lo.x; a[1] = lo.y; a[2] = lo.z; a[3] = lo.w;
          a[4] = hi.x; a[5] = hi.y; a[6] = hi.z; a[7] = hi.w;
          af[kc] = a;
        }
        f32x4 acc0 = (f32x4)0.f, acc1 = (f32x4)0.f, acc2 = (f32x4)0.f, acc3 = (f32x4)0.f;
#pragma unroll
        for (int kc = 0; kc < 2; ++kc) {
          acc0 = __builtin_amdgcn_mfma_scale_f32_16x16x128_f8f6f4(af[kc], wf[0][kc], acc0, 0, 0, 0, SCALE_ONE, 0, SCALE_ONE);
          acc1 = __builtin_amdgcn_mfma_scale_f32_16x16x128_f8f6f4(af[kc], wf[1][kc], acc1, 0, 0, 0, SCALE_ONE, 0, SCALE_ONE);
          acc2 = __builtin_amdgcn_mfma_scale_f32_16x16x128_f8f6f4(af[kc], wf[2][kc], acc2, 0, 0, 0, SCALE_ONE, 0, SCALE_ONE);
          acc3 = __builtin_amdgcn_mfma_scale_f32_16x16x128_f8f6f4(af[kc], wf[3][kc], acc3, 0, 0, 0, SCALE_ONE, 0, SCALE_ONE);
        }
        const uint word = (lg & 2) ? xpv.y : xpv.x;
        const uint h16 = (lg & 1) ? (word >> 16) : (word & 0xFFFFu);
        union { uint32_t u; float f; } xf; xf.u = h16 << 16;
        const float accsel = (lg & 2) ? ((lg & 1) ? acc3[0] : acc2[0])
                                      : ((lg & 1) ? acc1[0] : acc0[0]);
        const float p = accsel * INV_SCALE + xf.f;
        const float kk2 = (lg == 2) ? (2.f * LOG2E) : LOG2E;
        const float mm = (lg == 2) ? 2.f : 1.f;
        const float ex = __builtin_amdgcn_exp2f(kk2 * p);
        const float v = 1.f - mm * __builtin_amdgcn_rcpf(ex + 1.f);
        const float sf = __shfl(v, lr + 16);
        const float tg = __shfl(v, lr + 32);
        const float so = __shfl(v, lr + 48);
        cc = sf * cc + v * tg;
        const float e2 = __builtin_amdgcn_exp2f(2.f * LOG2E * cc);
        const float th = 1.f - 2.f * __builtin_amdgcn_rcpf(e2 + 1.f);
        const float h = so * th;
        if (lg == 0) {
          int q = __builtin_amdgcn_cvt_pk_fp8_f32(h * 16.f, h * 16.f, 0, false);
          hw[hcol] = (unsigned char)(q & 0xFF);
          h0pub[ts * 256 + hcol] = (unsigned char)(q & 0xFF);
        }
        __syncthreads();
      }
      // --- burst publish: 512 contiguous u64 agent-scope stores (coalesced) ---
      if (tid < 512) {
        const int r = tid >> 5, kq = tid & 31;
        const u64 v = *(const u64*)(h0pub + r * 256 + (kq << 3));
        __hip_atomic_store(hs64 + ((size_t)b * 32 + c) * 512 + r * 32 + kq, v,
                           __ATOMIC_RELAXED, __HIP_MEMORY_SCOPE_AGENT);
      }
      __syncthreads();  // per-wave vmcnt drain: publish complete before flag
      if (tid == 0)
        __hip_atomic_store(done0 + b, (unsigned)(c + 1),
                           __ATOMIC_RELAXED, __HIP_MEMORY_SCOPE_AGENT);
    }
  } else {
    // ================= layer 1 consumer (R13-proven; contiguous hs64 blocks) =================
    const f32x4 bias = *(const f32x4*)(b1p + (hcol << 2));
    __syncthreads();
    for (int c = 0; c < 32; ++c) {
      if (tid == 0) {
        while (__hip_atomic_load(done0 + b, __ATOMIC_RELAXED, __HIP_MEMORY_SCOPE_AGENT)
               < (unsigned)(c + 1))
          __builtin_amdgcn_s_sleep(2);
      }
      __syncthreads();
      // stage 16x256 fp8 h0 chunk -> LDS rows (pad 272), contiguous u64 atomic loads
      if (tid < 512) {
        const int r = tid >> 5, kq = tid & 31;
        const u64 v = __hip_atomic_load(
            hs64 + ((size_t)b * 32 + c) * 512 + r * 32 + kq,
            __ATOMIC_RELAXED, __HIP_MEMORY_SCOPE_AGENT);
        *(u64*)(h0l + r * 272 + (kq << 3)) = v;
      }
      __syncthreads();
      // chunk GEMM: A rows = 16 timesteps (lane lr), B = W_ih1 fp8 from L2
      f32x4 ga0 = (f32x4)0.f, ga1 = (f32x4)0.f, ga2 = (f32x4)0.f, ga3 = (f32x4)0.f;
#pragma unroll
      for (int kc = 0; kc < 2; ++kc) {
        const uint4* ap = (const uint4*)(h0l + lr * 272 + (kc << 7) + (lg << 5));
        uint4 alo = ap[0], ahi = ap[1];
        i32x8 a;
        a[0] = alo.x; a[1] = alo.y; a[2] = alo.z; a[3] = alo.w;
        a[4] = ahi.x; a[5] = ahi.y; a[6] = ahi.z; a[7] = ahi.w;
        const unsigned char* wb = W1p8 + (size_t)hcol * 256 + (kc << 7) + (lg << 5);
#pragma unroll
        for (int g = 0; g < 4; ++g) {
          const uint4* bp = (const uint4*)(wb + (size_t)g * 65536);
          uint4 blo = bp[0], bhi = bp[1];
          i32x8 bv;
          bv[0] = blo.x; bv[1] = blo.y; bv[2] = blo.z; bv[3] = blo.w;
          bv[4] = bhi.x; bv[5] = bhi.y; bv[6] = bhi.z; bv[7] = bhi.w;
          if (g == 0) ga0 = __builtin_amdgcn_mfma_scale_f32_16x16x128_f8f6f4(a, bv, ga0, 0, 0, 0, SCALE_ONE, 0, SCALE_ONE);
          if (g == 1) ga1 = __builtin_amdgcn_mfma_scale_f32_16x16x128_f8f6f4(a, bv, ga1, 0, 0, 0, SCALE_ONE, 0, SCALE_ONE);
          if (g == 2) ga2 = __builtin_amdgcn_mfma_scale_f32_16x16x128_f8f6f4(a, bv, ga2, 0, 0, 0, SCALE_ONE, 0, SCALE_ONE);
          if (g == 3) ga3 = __builtin_amdgcn_mfma_scale_f32_16x16x128_f8f6f4(a, bv, ga3, 0, 0, 0, SCALE_ONE, 0, SCALE_ONE);
        }
      }
      // xp chunk -> LDS bf16, bias folded; C row = 4*lg + i (timestep), gate-interleaved cols
#pragma unroll
      for (int i = 0; i < 4; ++i) {
        const int row = (lg << 2) + i;
        union { uint2 u; ushort s[4]; } pk;
        pk.s[0] = f2bf(ga0[i] * INV_SCALE + bias[0]);
        pk.s[1] = f2bf(ga1[i] * INV_SCALE + bias[1]);
        pk.s[2] = f2bf(ga2[i] * INV_SCALE + bias[2]);
        pk.s[3] = f2bf(ga3[i] * INV_SCALE + bias[3]);
        *(uint2*)(xpcu + row * 1024 + (hcol << 2)) = pk.u;
      }
      __syncthreads();
      // 16 recurrent steps (R7-verified structure, xp from LDS gate-interleaved)
      for (int ts = 0; ts < 16; ++ts) {
        const int t = (c << 4) + ts;
        const unsigned char* hr = hbb + ((t & 1) * 320);
        unsigned char* hw = hbb + (((t & 1) ^ 1) * 320);
        // xp read issued FIRST: its LDS latency hides under the MFMA chain
        const float xv = bf2f(xpcu[ts * 1024 + (hcol << 2) + lg]);
        i32x8 af[2];
#pragma unroll
        for (int kc = 0; kc < 2; ++kc) {
          const uint4* p = (const uint4*)(hr + kc * 128 + lg * 32);
          uint4 lo = p[0], hi = p[1];
          i32x8 a;
          a[0] = lo.x; a[1] = lo.y; a[2] = lo.z; a[3] = lo.w;
          a[4] = hi.x; a[5] = hi.y; a[6] = hi.z; a[7] = hi.w;
          af[kc] = a;
        }
        f32x4 acc0 = (f32x4)0.f, acc1 = (f32x4)0.f, acc2 = (f32x4)0.f, acc3 = (f32x4)0.f;
#pragma unroll
        for (int kc = 0; kc < 2; ++kc) {
          acc0 = __builtin_amdgcn_mfma_scale_f32_16x16x128_f8f6f4(af[kc], wf[0][kc], acc0, 0, 0, 0, SCALE_ONE, 0, SCALE_ONE);
          acc1 = __builtin_amdgcn_mfma_scale_f32_16x16x128_f8f6f4(af[kc], wf[1][kc], acc1, 0, 0, 0, SCALE_ONE, 0, SCALE_ONE);
          acc2 = __builtin_amdgcn_mfma_scale_f32_16x16x128_f8f6f4(af[kc], wf[2][kc], acc2, 0, 0, 0, SCALE_ONE, 0, SCALE_ONE);
          acc3 = __builtin_amdgcn_mfma_scale_f32_16x16x128_f8f6f4(af[kc], wf[3][kc], acc3, 0, 0, 0, SCALE_ONE, 0, SCALE_ONE);
        }
        const float accsel = (lg & 2) ? ((lg & 1) ? acc3[0] : acc2[0])
                                      : ((lg & 1) ? acc1[0] : acc0[0]);
        const float p = accsel * INV_SCALE + xv;
        const float kk2 = (lg == 2) ? (2.f * LOG2E) : LOG2E;
        const float mm = (lg == 2) ? 2.f : 1.f;
        const float ex = __builtin_amdgcn_exp2f(kk2 * p);
        const float v = 1.f - mm * __builtin_amdgcn_rcpf(ex + 1.f);
        const float sf = __shfl(v, lr + 16);
        const float tg = __shfl(v, lr + 32);
        const float so = __shfl(v, lr + 48);
        cc = sf * cc + v * tg;
        const float e2 = __builtin_amdgcn_exp2f(2.f * LOG2E * cc);
        const float th = 1.f - 2.f * __builtin_amdgcn_rcpf(e2 + 1.f);
        const float h = so * th;
        if (lg == 0) {
          int q = __builtin_amdgcn_cvt_pk_fp8_f32(h * 16.f, h * 16.f, 0, false);
          hw[hcol] = (unsigned char)(q & 0xFF);
          if (t == 511) hf[hcol] = h;
        }
        __syncthreads();
      }
    }
    // fc epilogue
    if (w == 0) {
      float s = 0.f;
#pragma unroll
      for (int j = 0; j < 4; ++j) {
        const int k = j * 64 + l;
        s += hf[k] * fcw[k];
      }
      s += __shfl_xor(s, 1);
      s += __shfl_xor(s, 2);
      s += __shfl_xor(s, 4);
      s += __shfl_xor(s, 8);
      s += __shfl_xor(s, 16);
      s += __shfl_xor(s, 32);
      if (l == 0) out[b] = sigm(s + fcb[0]);
    }
  }
}

// ---------------- launch ----------------
extern "C" void kernel_launch(void* const* d_in, const int* in_sizes, int n_in,
                              void* d_out, int out_size, void* d_ws, size_t ws_size,
                              hipStream_t stream)
{
  const int*   x    = (const int*)d_in[0];
  const float* emb  = (const float*)d_in[1];
  const float* fcw  = (const float*)d_in[2];
  const float* fcb  = (const float*)d_in[3];
  const float* Wih0 = (const float*)d_in[4];
  const float* Whh0 = (const float*)d_in[5];
  const float* bih0 = (const float*)d_in[6];
  const float* bhh0 = (const float*)d_in[7];
  const float* Wih1 = (const float*)d_in[8];
  const float* Whh1 = (const float*)d_in[9];
  const float* bih1 = (const float*)d_in[10];
  const float* bhh1 = (const float*)d_in[11];

  char* ws = (char*)d_ws;
  size_t off = 0;
  auto alloc = [&](size_t bytes) {
    void* p = ws + off;
    off = (off + bytes + 255) & ~(size_t)255;
    return p;
  };
  u64*           hs64  = (u64*)alloc(128ull * 32 * 512 * 8);
  ushort*        W0p   = (ushort*)alloc(1024ull * 128 * 2);
  unsigned char* W1p8  = (unsigned char*)alloc(1024ull * 256);
  float*         b0p   = (float*)alloc(1024 * 4);
  float*         b1p   = (float*)alloc(1024 * 4);
  unsigned int*  done0 = (unsigned int*)alloc(128 * 4);

  prep_kernel<<<256, 256, 0, stream>>>(Wih0, Wih1, bih0, bhh0, bih1, bhh1,
                                       W0p, W1p8, b0p, b1p, done0);
  mega_scan<<<256, 1024, 0, stream>>>(x, emb, W0p, b0p, Whh0, Whh1, W1p8, b1p,
                                      hs64, done0, fcw, fcb, (float*)d_out);
}